// Round 1
// baseline (434.018 us; speedup 1.0000x reference)
//
#include <hip/hip_runtime.h>

typedef __attribute__((ext_vector_type(4))) float f32x4;
typedef __attribute__((ext_vector_type(8))) short short8;
typedef __attribute__((ext_vector_type(4))) unsigned short us4;

#define BH_ 128
#define N_ 4096
#define D_ 64
#define M_ 256
#define NORMF 0.35355339059327373f
#define EPSF 1e-4f

static __device__ __forceinline__ unsigned short f2bf(float f) {
  unsigned int u = __float_as_uint(f);
  u += 0x7FFFu + ((u >> 16) & 1u);
  return (unsigned short)(u >> 16);
}
static __device__ __forceinline__ float bf2f(unsigned short s) {
  return __uint_as_float(((unsigned int)s) << 16);
}

// ---------------------------------------------------------------------------
// K pass: for each (head, n-chunk): dd = K*P^T (MFMA), w = exp(dd - diag)
// (unshifted; global max tracked separately), ctx_partial += w^T * V (MFMA),
// kexp_partial += sum_n w, vsum_partial += sum_n v, gmax via atomicMax.
// ---------------------------------------------------------------------------
__global__ __launch_bounds__(256, 2)
void perf_kpass(const float* __restrict__ kp, const float* __restrict__ vp,
                const float* __restrict__ proj, float* __restrict__ ctxp,
                float* __restrict__ kexpp, float* __restrict__ vsump,
                unsigned int* __restrict__ gmaxb, int nchunk) {
  const int bh = blockIdx.x & (BH_ - 1);
  const int chunk = blockIdx.x >> 7;
  const int chunkrows = N_ / nchunk;
  const int tiles = chunkrows >> 5;
  const int t = threadIdx.x;
  const int wid = t >> 6;
  const int lane = t & 63;
  const int g = lane >> 4;
  const int c = lane & 15;

  __shared__ __align__(16) unsigned short sX[32][72];
  __shared__ __align__(16) unsigned short sVt[64][40];
  __shared__ __align__(16) unsigned short sW[256][40];
  __shared__ float sDiag[32];
  __shared__ float sVsum[64];
  __shared__ float sGm[4];

  // P fragments (B operand of GEMM1), data_normalizer folded in. Constant
  // per block; wave 'wid' owns m-range [wid*64, wid*64+64).
  short8 pfrag[4][2];
#pragma unroll
  for (int mt = 0; mt < 4; ++mt)
#pragma unroll
    for (int kk = 0; kk < 2; ++kk) {
      const float* src = proj + (wid * 64 + mt * 16 + c) * 64 + kk * 32 + g * 8;
      short8 v;
#pragma unroll
      for (int j = 0; j < 8; ++j) v[j] = (short)f2bf(src[j] * NORMF);
      pfrag[mt][kk] = v;
    }

  f32x4 ctx[4][4];
#pragma unroll
  for (int i = 0; i < 4; ++i)
#pragma unroll
    for (int j = 0; j < 4; ++j) ctx[i][j] = (f32x4){0.f, 0.f, 0.f, 0.f};

  float kexpreg[4] = {0.f, 0.f, 0.f, 0.f};
  float vsum0 = 0.f, vsum1 = 0.f, vsum2 = 0.f, vsum3 = 0.f;
  float gm = -1e30f;

  const float* kb0 = kp + ((size_t)bh * N_ + (size_t)chunk * chunkrows) * D_;
  const float* vb0 = vp + ((size_t)bh * N_ + (size_t)chunk * chunkrows) * D_;

  for (int nt = 0; nt < tiles; ++nt) {
    const float* kb = kb0 + nt * (32 * 64);
    const float* vb = vb0 + nt * (32 * 64);
    // ---- stage K rows (bf16), diag (f32), V transposed (bf16), vsum ----
#pragma unroll
    for (int hh = 0; hh < 2; ++hh) {
      int f = t + hh * 256;
      int row = f >> 4;
      int c4 = f & 15;
      f32x4 x = *(const f32x4*)(kb + row * 64 + c4 * 4);
      float ss = x[0] * x[0] + x[1] * x[1] + x[2] * x[2] + x[3] * x[3];
      ss += __shfl_xor(ss, 1);
      ss += __shfl_xor(ss, 2);
      ss += __shfl_xor(ss, 4);
      ss += __shfl_xor(ss, 8);
      if (c4 == 0) sDiag[row] = 0.0625f * ss;  // 0.5 * d^-0.5 * sum(x^2)
      us4 xb = {f2bf(x[0]), f2bf(x[1]), f2bf(x[2]), f2bf(x[3])};
      *(us4*)&sX[row][c4 * 4] = xb;
      f32x4 vv = *(const f32x4*)(vb + row * 64 + c4 * 4);
      vsum0 += vv[0]; vsum1 += vv[1]; vsum2 += vv[2]; vsum3 += vv[3];
      // rotated write order spreads LDS banks for the transposed store
#pragma unroll
      for (int jj = 0; jj < 4; ++jj) {
        int j = (jj + t) & 3;
        float val = (j == 0) ? vv[0] : (j == 1) ? vv[1] : (j == 2) ? vv[2] : vv[3];
        sVt[c4 * 4 + j][row] = f2bf(val);
      }
    }
    __syncthreads();

    // ---- GEMM1: dd[32n x 256m] = X * P^T ----
    short8 afr[2][2];
#pragma unroll
    for (int nh1 = 0; nh1 < 2; ++nh1)
#pragma unroll
      for (int kk = 0; kk < 2; ++kk)
        afr[nh1][kk] = *(const short8*)&sX[nh1 * 16 + c][kk * 32 + g * 8];

    f32x4 acc1[2][4];
#pragma unroll
    for (int i = 0; i < 2; ++i)
#pragma unroll
      for (int j = 0; j < 4; ++j) acc1[i][j] = (f32x4){0.f, 0.f, 0.f, 0.f};
#pragma unroll
    for (int kk = 0; kk < 2; ++kk)
#pragma unroll
      for (int nh1 = 0; nh1 < 2; ++nh1)
#pragma unroll
        for (int mt = 0; mt < 4; ++mt)
          acc1[nh1][mt] = __builtin_amdgcn_mfma_f32_16x16x32_bf16(
              afr[nh1][kk], pfrag[mt][kk], acc1[nh1][mt], 0, 0, 0);

    // ---- w = exp(dd - diag) (unshifted), write w^T to LDS, track stats ----
#pragma unroll
    for (int nh1 = 0; nh1 < 2; ++nh1)
#pragma unroll
      for (int mt = 0; mt < 4; ++mt) {
        int m = wid * 64 + mt * 16 + c;
        unsigned short wp[4];
#pragma unroll
        for (int r = 0; r < 4; ++r) {
          float dd = acc1[nh1][mt][r];
          gm = fmaxf(gm, dd);
          int n = nh1 * 16 + g * 4 + r;
          float w = __expf(dd - sDiag[n]);
          unsigned short wb = f2bf(w);
          kexpreg[mt] += bf2f(wb);  // consistent with bf16 w used in GEMM2
          wp[r] = wb;
        }
        us4 w4 = {wp[0], wp[1], wp[2], wp[3]};
        *(us4*)&sW[m][nh1 * 16 + g * 4] = w4;
      }
    __syncthreads();

    // ---- GEMM2: ctx[256m x 64e] += w^T * V ----
    short8 awt[4], bvv[4];
#pragma unroll
    for (int mt2 = 0; mt2 < 4; ++mt2)
      awt[mt2] = *(const short8*)&sW[wid * 64 + mt2 * 16 + c][g * 8];
#pragma unroll
    for (int et = 0; et < 4; ++et)
      bvv[et] = *(const short8*)&sVt[et * 16 + c][g * 8];
#pragma unroll
    for (int mt2 = 0; mt2 < 4; ++mt2)
#pragma unroll
      for (int et = 0; et < 4; ++et)
        ctx[mt2][et] = __builtin_amdgcn_mfma_f32_16x16x32_bf16(
            awt[mt2], bvv[et], ctx[mt2][et], 0, 0, 0);
    __syncthreads();
  }

  // ---- write per-chunk partials ----
#pragma unroll
  for (int mt2 = 0; mt2 < 4; ++mt2)
#pragma unroll
    for (int et = 0; et < 4; ++et) {
      int m0 = wid * 64 + mt2 * 16 + g * 4;
      int e = et * 16 + c;
      size_t base = (((size_t)chunk * BH_ + bh) * 64 + e) * 256 + m0;
      *(f32x4*)(ctxp + base) = ctx[mt2][et];
    }
#pragma unroll
  for (int mt = 0; mt < 4; ++mt) {
    float s = kexpreg[mt];
    s += __shfl_xor(s, 16);
    s += __shfl_xor(s, 32);
    if (lane < 16)
      kexpp[((size_t)chunk * BH_ + bh) * 256 + wid * 64 + mt * 16 + lane] = s;
  }
  if (t < 64) sVsum[t] = 0.f;
  __syncthreads();
  atomicAdd(&sVsum[(t & 15) * 4 + 0], vsum0);
  atomicAdd(&sVsum[(t & 15) * 4 + 1], vsum1);
  atomicAdd(&sVsum[(t & 15) * 4 + 2], vsum2);
  atomicAdd(&sVsum[(t & 15) * 4 + 3], vsum3);
  __syncthreads();
  if (t < 64) vsump[((size_t)chunk * BH_ + bh) * 64 + t] = sVsum[t];

  gm = fmaxf(gm, __shfl_xor(gm, 1));
  gm = fmaxf(gm, __shfl_xor(gm, 2));
  gm = fmaxf(gm, __shfl_xor(gm, 4));
  gm = fmaxf(gm, __shfl_xor(gm, 8));
  gm = fmaxf(gm, __shfl_xor(gm, 16));
  gm = fmaxf(gm, __shfl_xor(gm, 32));
  if (lane == 0) sGm[wid] = gm;
  __syncthreads();
  if (t == 0) {
    float mm = fmaxf(fmaxf(sGm[0], sGm[1]), fmaxf(sGm[2], sGm[3]));
    atomicMax((int*)gmaxb, __float_as_int(mm));  // positive floats: bit-monotone
  }
}

// ---------------------------------------------------------------------------
// Rescale: CTX = e^-gmax * sum_chunk(ctx_partial) + eps*vsum  -> bf16 [bh][e][m]
//          KC  = e^-gmax * sum_chunk(kexp)        + eps*N     -> f32  [bh][m]
// ---------------------------------------------------------------------------
__global__ void perf_rescale(const float* __restrict__ ctxp,
                             const float* __restrict__ kexpp,
                             const float* __restrict__ vsump,
                             float* __restrict__ kcw,
                             unsigned short* __restrict__ ctxt,
                             const unsigned int* __restrict__ gmaxb, int nchunk) {
  const int bh = blockIdx.x;
  const int t = threadIdx.x;
  const float gmax = __uint_as_float(*gmaxb);
  const float s = __expf(-gmax);
  float acc = 0.f;
  for (int cc = 0; cc < nchunk; ++cc)
    acc += kexpp[((size_t)cc * BH_ + bh) * 256 + t];
  kcw[bh * 256 + t] = s * acc + EPSF * (float)N_;
  for (int e = 0; e < 64; ++e) {
    float vs = 0.f;
    for (int cc = 0; cc < nchunk; ++cc)
      vs += vsump[((size_t)cc * BH_ + bh) * 64 + e];
    float a2 = 0.f;
    for (int cc = 0; cc < nchunk; ++cc)
      a2 += ctxp[(((size_t)cc * BH_ + bh) * 64 + e) * 256 + t];
    ctxt[((size_t)bh * 64 + e) * 256 + t] = f2bf(s * a2 + EPSF * vs);
  }
}

// ---------------------------------------------------------------------------
// Q pass: dd = Q*P^T, rowmax, qt = exp(dd - diag - rowmax) + eps,
// den = qt . KC, out = (qt * CTX) / den.  CTX fragments live in registers.
// ---------------------------------------------------------------------------
__global__ __launch_bounds__(256, 2)
void perf_qpass(const float* __restrict__ qp, const float* __restrict__ proj,
                const unsigned short* __restrict__ ctxt,
                const float* __restrict__ kc, float* __restrict__ outp) {
  const int bh = blockIdx.x & (BH_ - 1);
  const int chunk = blockIdx.x >> 7;  // 0..7, 512 rows each
  const int t = threadIdx.x;
  const int wid = t >> 6;
  const int lane = t & 63;
  const int g = lane >> 4;
  const int c = lane & 15;
  const int nh = wid >> 1;  // output n-half owned in GEMM2
  const int ep = wid & 1;   // output e-pair owned in GEMM2

  __shared__ __align__(16) unsigned short sX[32][72];
  __shared__ __align__(16) unsigned short sQt[32][264];
  __shared__ float sDiag[32];
  __shared__ float sRmax[32];
  __shared__ float sRowPart[4][33];
  __shared__ float sDenPart[4][33];

  short8 pfrag[4][2];
#pragma unroll
  for (int mt = 0; mt < 4; ++mt)
#pragma unroll
    for (int kk = 0; kk < 2; ++kk) {
      const float* src = proj + (wid * 64 + mt * 16 + c) * 64 + kk * 32 + g * 8;
      short8 v;
#pragma unroll
      for (int j = 0; j < 8; ++j) v[j] = (short)f2bf(src[j] * NORMF);
      pfrag[mt][kk] = v;
    }

  short8 cfrag[2][8];
#pragma unroll
  for (int fi = 0; fi < 2; ++fi)
#pragma unroll
    for (int kk2 = 0; kk2 < 8; ++kk2)
      cfrag[fi][kk2] = *(const short8*)&ctxt[(((size_t)bh * 64) +
                                             (ep * 2 + fi) * 16 + c) * 256 +
                                            kk2 * 32 + g * 8];
  float kcreg[4];
#pragma unroll
  for (int mt = 0; mt < 4; ++mt)
    kcreg[mt] = kc[bh * 256 + wid * 64 + mt * 16 + c];

  const float* qb0 = qp + ((size_t)bh * N_ + (size_t)chunk * 512) * D_;
  float* ob0 = outp + ((size_t)bh * N_ + (size_t)chunk * 512) * D_;

  for (int nt = 0; nt < 16; ++nt) {
    const float* qb = qb0 + nt * (32 * 64);
#pragma unroll
    for (int hh = 0; hh < 2; ++hh) {
      int f = t + hh * 256;
      int row = f >> 4;
      int c4 = f & 15;
      f32x4 x = *(const f32x4*)(qb + row * 64 + c4 * 4);
      float ss = x[0] * x[0] + x[1] * x[1] + x[2] * x[2] + x[3] * x[3];
      ss += __shfl_xor(ss, 1);
      ss += __shfl_xor(ss, 2);
      ss += __shfl_xor(ss, 4);
      ss += __shfl_xor(ss, 8);
      if (c4 == 0) sDiag[row] = 0.0625f * ss;
      us4 xb = {f2bf(x[0]), f2bf(x[1]), f2bf(x[2]), f2bf(x[3])};
      *(us4*)&sX[row][c4 * 4] = xb;
    }
    __syncthreads();

    short8 afr[2][2];
#pragma unroll
    for (int nh1 = 0; nh1 < 2; ++nh1)
#pragma unroll
      for (int kk = 0; kk < 2; ++kk)
        afr[nh1][kk] = *(const short8*)&sX[nh1 * 16 + c][kk * 32 + g * 8];
    f32x4 acc1[2][4];
#pragma unroll
    for (int i = 0; i < 2; ++i)
#pragma unroll
      for (int j = 0; j < 4; ++j) acc1[i][j] = (f32x4){0.f, 0.f, 0.f, 0.f};
#pragma unroll
    for (int kk = 0; kk < 2; ++kk)
#pragma unroll
      for (int nh1 = 0; nh1 < 2; ++nh1)
#pragma unroll
        for (int mt = 0; mt < 4; ++mt)
          acc1[nh1][mt] = __builtin_amdgcn_mfma_f32_16x16x32_bf16(
              afr[nh1][kk], pfrag[mt][kk], acc1[nh1][mt], 0, 0, 0);

    // rowmax over all 256 m (wave-local 64 m via shfl, cross-wave via LDS)
#pragma unroll
    for (int nh1 = 0; nh1 < 2; ++nh1)
#pragma unroll
      for (int r = 0; r < 4; ++r) {
        float mx = fmaxf(fmaxf(acc1[nh1][0][r], acc1[nh1][1][r]),
                         fmaxf(acc1[nh1][2][r], acc1[nh1][3][r]));
        mx = fmaxf(mx, __shfl_xor(mx, 1));
        mx = fmaxf(mx, __shfl_xor(mx, 2));
        mx = fmaxf(mx, __shfl_xor(mx, 4));
        mx = fmaxf(mx, __shfl_xor(mx, 8));
        if (c == 0) sRowPart[wid][nh1 * 16 + g * 4 + r] = mx;
      }
    __syncthreads();
    if (t < 32)
      sRmax[t] = fmaxf(fmaxf(sRowPart[0][t], sRowPart[1][t]),
                       fmaxf(sRowPart[2][t], sRowPart[3][t]));
    __syncthreads();

    unsigned short qtv[2][4][4];
    float denp[2][4];
#pragma unroll
    for (int nh1 = 0; nh1 < 2; ++nh1)
#pragma unroll
      for (int r = 0; r < 4; ++r) denp[nh1][r] = 0.f;
#pragma unroll
    for (int nh1 = 0; nh1 < 2; ++nh1)
#pragma unroll
      for (int mt = 0; mt < 4; ++mt)
#pragma unroll
        for (int r = 0; r < 4; ++r) {
          int n = nh1 * 16 + g * 4 + r;
          float qt = __expf(acc1[nh1][mt][r] - sDiag[n] - sRmax[n]) + EPSF;
          unsigned short qb16 = f2bf(qt);
          denp[nh1][r] += bf2f(qb16) * kcreg[mt];
          qtv[nh1][mt][r] = qb16;
        }
#pragma unroll
    for (int nh1 = 0; nh1 < 2; ++nh1)
#pragma unroll
      for (int mt = 0; mt < 4; ++mt)
#pragma unroll
        for (int r = 0; r < 4; ++r)
          sQt[nh1 * 16 + g * 4 + r][wid * 64 + mt * 16 + c] = qtv[nh1][mt][r];
#pragma unroll
    for (int nh1 = 0; nh1 < 2; ++nh1)
#pragma unroll
      for (int r = 0; r < 4; ++r) {
        float s = denp[nh1][r];
        s += __shfl_xor(s, 1);
        s += __shfl_xor(s, 2);
        s += __shfl_xor(s, 4);
        s += __shfl_xor(s, 8);
        if (c == 0) sDenPart[wid][nh1 * 16 + g * 4 + r] = s;
      }
    __syncthreads();

    // GEMM2: out[32n x 64e] = qt * CTX^T ; each wave owns (nh, e-pair)
    f32x4 acc2[2];
    acc2[0] = (f32x4){0.f, 0.f, 0.f, 0.f};
    acc2[1] = (f32x4){0.f, 0.f, 0.f, 0.f};
#pragma unroll
    for (int kk2 = 0; kk2 < 8; ++kk2) {
      short8 a2 = *(const short8*)&sQt[nh * 16 + c][kk2 * 32 + g * 8];
      acc2[0] = __builtin_amdgcn_mfma_f32_16x16x32_bf16(a2, cfrag[0][kk2], acc2[0], 0, 0, 0);
      acc2[1] = __builtin_amdgcn_mfma_f32_16x16x32_bf16(a2, cfrag[1][kk2], acc2[1], 0, 0, 0);
    }
#pragma unroll
    for (int r = 0; r < 4; ++r) {
      int n = nh * 16 + g * 4 + r;
      float den = sDenPart[0][n] + sDenPart[1][n] + sDenPart[2][n] + sDenPart[3][n];
      float rinv = 1.0f / den;
#pragma unroll
      for (int fi = 0; fi < 2; ++fi) {
        int e = (ep * 2 + fi) * 16 + c;
        ob0[((size_t)(nt * 32 + n)) * 64 + e] = acc2[fi][r] * rinv;
      }
    }
    __syncthreads();
  }
}

extern "C" void kernel_launch(void* const* d_in, const int* in_sizes, int n_in,
                              void* d_out, int out_size, void* d_ws, size_t ws_size,
                              hipStream_t stream) {
  (void)in_sizes; (void)n_in; (void)out_size;
  const float* qp = (const float*)d_in[0];
  const float* kp = (const float*)d_in[1];
  const float* vp = (const float*)d_in[2];
  const float* proj = (const float*)d_in[3];
  float* outp = (float*)d_out;

  int nchunk = 4;
  while (nchunk > 1) {
    size_t fl = 64 + (size_t)nchunk * (2097152 + 32768 + 8192) + 32768;
    size_t needed = fl * 4 + (size_t)128 * 64 * 256 * 2;
    if (needed <= ws_size) break;
    nchunk >>= 1;
  }

  float* wsf = (float*)d_ws;
  unsigned int* gmaxb = (unsigned int*)d_ws;
  float* ctxp = wsf + 64;
  float* kexpp = ctxp + (size_t)nchunk * 128 * 64 * 256;
  float* vsump = kexpp + (size_t)nchunk * 128 * 256;
  float* kcw = vsump + (size_t)nchunk * 128 * 64;
  unsigned short* ctxt = (unsigned short*)(kcw + 128 * 256);

  hipMemsetAsync(d_ws, 0, 16, stream);  // init gmax bits (positive-float max)
  hipLaunchKernelGGL(perf_kpass, dim3(128 * nchunk), dim3(256), 0, stream,
                     kp, vp, proj, ctxp, kexpp, vsump, gmaxb, nchunk);
  hipLaunchKernelGGL(perf_rescale, dim3(128), dim3(256), 0, stream,
                     ctxp, kexpp, vsump, kcw, ctxt, gmaxb, nchunk);
  hipLaunchKernelGGL(perf_qpass, dim3(128 * 8), dim3(256), 0, stream,
                     qp, proj, ctxt, kcw, outp);
}